// Round 12
// baseline (66.653 us; speedup 1.0000x reference)
//
#include <hip/hip_runtime.h>
#include <math.h>

// HSTU jagged attention, MFMA bf16, DMA-staged, static XCD-affine LPT schedule.
// out = (silu(Q K^T) / N * mask) V, no softmax. H=8, D=DV=64, N=1024.
// Mask (exact collapse): valid(n,m) = (m < thr(n)) | (m == n),
//   thr(n) = (an>0 ? an : M) + c - 1, an = clamp(n-c+1,0,M), M = L-c+1-ncand.
// R12: tile-image prepass replaced by {bf16 K row-major + bf16 V^T} buffers;
// main kernel DMAs with PRE-SWIZZLED per-lane global sources (LDS dest linear,
// source col = ((l&7)^(l>>3))*8 is lane-constant). LDS images bit-identical
// to R11. Prep is one kernel (K convert + V transpose + sched in block 0).

#define HH      8
#define DDIM    64
#define QT      64
#define KT      64
#define STRIDE  512
#define NMAX    1024
#define NORD    16
#define TILE_HW 8192
#define NBLK    1024
#define SLOTS   8

typedef __attribute__((ext_vector_type(8))) short short8;
typedef __attribute__((ext_vector_type(4))) float f32x4;
typedef __attribute__((ext_vector_type(4))) uint  u32x4;

static __device__ __forceinline__ uint pk2(float a, float b) {
  uint r;
  asm("v_cvt_pk_bf16_f32 %0, %1, %2" : "=v"(r) : "v"(a), "v"(b));
  return r;
}

static __device__ __forceinline__ void dma16(const ushort* g, ushort* l) {
  __builtin_amdgcn_global_load_lds(
      (const __attribute__((address_space(1))) void*)g,
      (__attribute__((address_space(3))) void*)l, 16, 0, 0);
}

// ---- pre-pass: K fp32->bf16 row-major; V fp32->bf16 transposed
//      vbfT[(h*64+dv)][b*1024+m]; block (0,0,0) also emits the LPT schedule.
__global__ void prep(const float* __restrict__ tk,
                     const float* __restrict__ tv,
                     ushort* __restrict__ kbf,
                     ushort* __restrict__ vbfT,
                     const int* __restrict__ offsets,
                     short* __restrict__ sched, int Bb) {
  const int mt = blockIdx.x, h = blockIdx.y, b = blockIdx.z;
  const int off = offsets[b];
  const int L   = offsets[b + 1] - off;
  const int tid = threadIdx.x;
  const int VTROW = Bb * NMAX;
  const bool sched_block = (mt == 0 && h == 0 && b == 0);

  __shared__ ushort tr[64][66];

  if (mt * 64 < L) {
    const int row = tid >> 2;
    const int c0  = (tid & 3) * 16;
    const int m   = mt * 64 + row;
    const int mcl = min(m, L - 1);

    // K rows -> kbf (row-major bf16), only real rows
    if (m < L) {
      const float* s = tk + (size_t)(off + m) * STRIDE + h * DDIM + c0;
      float4 a = *(const float4*)(s),      b4 = *(const float4*)(s + 4);
      float4 c4 = *(const float4*)(s + 8), d4 = *(const float4*)(s + 12);
      uint u[8];
      u[0] = pk2(a.x, a.y);   u[1] = pk2(a.z, a.w);
      u[2] = pk2(b4.x, b4.y); u[3] = pk2(b4.z, b4.w);
      u[4] = pk2(c4.x, c4.y); u[5] = pk2(c4.z, c4.w);
      u[6] = pk2(d4.x, d4.y); u[7] = pk2(d4.z, d4.w);
      ushort* o = kbf + (size_t)(off + m) * STRIDE + h * DDIM + c0;
      *(uint4*)(o)     = make_uint4(u[0], u[1], u[2], u[3]);
      *(uint4*)(o + 8) = make_uint4(u[4], u[5], u[6], u[7]);
    }
    // V rows -> LDS (clamped duplicate beyond L; masked downstream)
    {
      const float* s = tv + (size_t)(off + mcl) * STRIDE + h * DDIM + c0;
      float4 a = *(const float4*)(s),      b4 = *(const float4*)(s + 4);
      float4 c4 = *(const float4*)(s + 8), d4 = *(const float4*)(s + 12);
      uint u[8];
      u[0] = pk2(a.x, a.y);   u[1] = pk2(a.z, a.w);
      u[2] = pk2(b4.x, b4.y); u[3] = pk2(b4.z, b4.w);
      u[4] = pk2(c4.x, c4.y); u[5] = pk2(c4.z, c4.w);
      u[6] = pk2(d4.x, d4.y); u[7] = pk2(d4.z, d4.w);
#pragma unroll
      for (int j = 0; j < 8; ++j) *(uint*)&tr[row][c0 + 2 * j] = u[j];
    }
    __syncthreads();
    // transpose out: dv = row, m-chunk = c0
    {
      const int dv = tid >> 2;
      const int tc = (tid & 3) * 16;
      uint o[8];
#pragma unroll
      for (int j = 0; j < 8; ++j)
        o[j] = (uint)tr[tc + 2 * j][dv] | ((uint)tr[tc + 2 * j + 1][dv] << 16);
      ushort* orow = vbfT + (size_t)(h * DDIM + dv) * VTROW + b * NMAX + mt * 64 + tc;
      *(uint4*)(orow)     = make_uint4(o[0], o[1], o[2], o[3]);
      *(uint4*)(orow + 8) = make_uint4(o[4], o[5], o[6], o[7]);
    }
  }

  // ---- schedule (block (0,0,0) only): deterministic, atomics-free ----
  if (!sched_block) return;
  for (int i = tid; i < NBLK * SLOTS; i += 256) sched[i] = (short)-1;
  __syncthreads();
  if (tid < 64) {
    const int g = tid >> 3, hh = tid & 7;
    int nq[16];
    {
      int o0 = offsets[0];
      for (int bb = 0; bb < Bb; ++bb) {
        int o1 = offsets[bb + 1];
        nq[bb] = (o1 - o0 + QT - 1) / QT;
        o0 = o1;
      }
    }
    int gb0 = -1, gb1 = -1;
    for (int bb = 0; bb < Bb; ++bb) {
      int r = 0;
      for (int j = 0; j < Bb; ++j)
        r += (nq[j] > nq[bb]) || (nq[j] == nq[bb] && j < bb);
      int gg = (r < Bb / 2) ? (r & 7) : ((Bb - 1 - r) & 7);
      if (gg == g) { if (r < Bb / 2) gb0 = bb; else gb1 = bb; }
    }
    int i = 0;
    for (int cst = 16; cst >= 1; --cst) {
      for (int s = 0; s < 2; ++s) {
        int bb = (s == 0) ? gb0 : gb1;
        if (bb < 0) continue;
        const int q = nq[bb];
        for (int which = 0; which < 2; ++which) {
          int qt = -1;
          if (which == 0 && cst == q) qt = 0;
          if (which == 1 && cst <= q && cst >= 2) qt = cst - 1;
          if (qt < 0) continue;
          const int rank = i * 8 + hh;
          const int pos  = rank & 255;
          const int lb   = (pos < 128) ? pos : 255 - pos;
          const int blk  = g + 8 * lb;
          const int slot = (pos < 128) ? 2 * (rank >> 8) : 2 * (rank >> 8) + 1;
          if (slot < SLOTS)
            sched[blk * SLOTS + slot] = (short)((bb << 7) | (hh << 4) | qt);
          ++i;
        }
      }
    }
  }
}

__global__ void zero_ctr(uint* ctr) { *ctr = 0u; }

// ---- main: DMA-staged (pre-swizzled sources), statically scheduled ----
__launch_bounds__(256, 4)
__global__ void hstu_s(const float* __restrict__ tq,
                       const ushort* __restrict__ kbf,
                       const ushort* __restrict__ vbfT,
                       const short* __restrict__ sched,
                       const int* __restrict__ offsets,
                       const int* __restrict__ pN,
                       const int* __restrict__ ncand,
                       const int* __restrict__ nctx,
                       float* __restrict__ out, int Tm1, int Bb) {
  __shared__ ushort KV[2][TILE_HW];  // double-buffered [K 8KB | V^T 8KB]  32 KB
  __shared__ ushort Ps[4 * 1024];    // per-wave P strips                  8 KB

  const int tid  = threadIdx.x;
  const int w    = tid >> 6;
  const int lane = tid & 63;
  const int lo   = lane & 15;
  const int hi   = lane >> 4;
  const int VTROW = Bb * NMAX;

  // lane-constant swizzled source column: dest col (l&7)*8 ^ ((row&7)<<3), row&7 = l>>3
  const int lr  = lane >> 3;
  const int csw = ((lane & 7) ^ lr) * 8;

  const float invN = 1.0f / (float)pN[0];
  ushort* Pw = &Ps[w * 1024];
  const short* my = sched + blockIdx.x * SLOTS;

  for (int slot = 0; slot < SLOTS; ++slot) {
    const int e = my[slot];
    if (e < 0) return;
    const int b = (e >> 7) & 15, h = (e >> 4) & 7, qt = e & 15;
    const int off = offsets[b];
    const int L   = offsets[b + 1] - off;
    const int n0  = qt * QT;
    if (n0 >= L) continue;

    const int c = nctx[b];
    const int M = L - c + 1 - ncand[b];
    const int m_hi  = (n0 < c) ? L : min(n0 + QT, L);
    const int niter = (m_hi + KT - 1) / KT;

    // per-item per-lane DMA source bases (swizzle baked into csw)
    const ushort* pK = kbf + (size_t)(off + w * 16 + lr) * STRIDE + h * DDIM + csw;
    const ushort* pV = vbfT + (size_t)(h * DDIM + w * 16 + lr) * VTROW
                       + (size_t)b * NMAX + csw;

    __syncthreads();                         // prev item's LDS fully consumed

    // prologue: DMA tile 0 into KV[0] (4 x 1KB per wave = 16 KB/block)
    {
      ushort* dK = &KV[0][w * 1024];
      ushort* dV = &KV[0][4096 + w * 1024];
      dma16(pK,                    dK);
      dma16(pK + 8 * STRIDE,       dK + 512);
      dma16(pV,                    dV);
      dma16(pV + (size_t)8 * VTROW, dV + 512);
    }

    // Q -> registers (frag: entity row = w*16+lo, k = ks*32 + hi*8 + 0..7)
    short8 qf[2];
    {
      int qr = min(off + n0 + w * 16 + lo, Tm1);
      const float* qp = tq + (size_t)qr * STRIDE + h * DDIM + hi * 8;
      float4 qa = *(const float4*)(qp);
      float4 qb = *(const float4*)(qp + 4);
      float4 qc = *(const float4*)(qp + 32);
      float4 qd = *(const float4*)(qp + 36);
      u32x4 v0 = {pk2(qa.x, qa.y), pk2(qa.z, qa.w), pk2(qb.x, qb.y), pk2(qb.z, qb.w)};
      u32x4 v1 = {pk2(qc.x, qc.y), pk2(qc.z, qc.w), pk2(qd.x, qd.y), pk2(qd.z, qd.w)};
      qf[0] = __builtin_bit_cast(short8, v0);
      qf[1] = __builtin_bit_cast(short8, v1);
    }

    // per-lane mask scalars (q-row = n): valid = nok & ((m < thr) | (m == n))
    const int  n   = n0 + w * 16 + lo;
    const int  an  = min(max(n - c + 1, 0), M);
    const int  thr = (an > 0 ? an : M) + c - 1;
    const bool nok = n < L;

    f32x4 oacc[4];
#pragma unroll
    for (int i = 0; i < 4; ++i) oacc[i] = (f32x4){0.f, 0.f, 0.f, 0.f};

    for (int t = 0; t < niter; ++t) {
      __syncthreads();   // drains tile-t DMA; gates buf (t+1)&1 reuse

      if (t + 1 < niter) {
        const ushort* sk = pK + (size_t)(t + 1) * (KT * STRIDE);
        const ushort* sv = pV + (t + 1) * KT;
        ushort* dK = &KV[(t + 1) & 1][w * 1024];
        ushort* dV = &KV[(t + 1) & 1][4096 + w * 1024];
        dma16(sk,                    dK);
        dma16(sk + 8 * STRIDE,       dK + 512);
        dma16(sv,                    dV);
        dma16(sv + (size_t)8 * VTROW, dV + 512);
      }

      const ushort* Kb = KV[t & 1];
      const ushort* Vb = Kb + 4096;
      const int m0 = t * KT;

      // S^T = K Q^T (swapped): lane holds P[q=lo][m = m0+kc*16+4*hi+r]
#pragma unroll
      for (int kc = 0; kc < 4; ++kc) {
        const int krw = kc * 16 + lo;
        const int ksw = (krw & 7) << 3;
        short8 kf0 = *(const short8*)&Kb[krw * 64 + ((hi * 8) ^ ksw)];
        short8 kf1 = *(const short8*)&Kb[krw * 64 + ((32 + hi * 8) ^ ksw)];
        f32x4 s4 = (f32x4){0.f, 0.f, 0.f, 0.f};
        s4 = __builtin_amdgcn_mfma_f32_16x16x32_bf16(kf0, qf[0], s4, 0, 0, 0);
        s4 = __builtin_amdgcn_mfma_f32_16x16x32_bf16(kf1, qf[1], s4, 0, 0, 0);
        const int mb = m0 + kc * 16 + 4 * hi;
        float pp[4];
#pragma unroll
        for (int r = 0; r < 4; ++r) {
          const int mm = mb + r;
          const bool valid = nok & ((mm < thr) | (mm == n));
          float s = valid ? s4[r] : 0.f;     // silu(0)=0; no NaN path
          pp[r] = s * invN * __builtin_amdgcn_rcpf(1.f + __expf(-s));
        }
        const int col = kc * 16 + 4 * hi;    // 4-aligned -> 8B packed write
        *(uint2*)&Pw[lo * 64 + (col ^ ((lo & 7) << 3))] =
            make_uint2(pk2(pp[0], pp[1]), pk2(pp[2], pp[3]));
      }

      // O += P V (wave-private P round-trip, no barrier)
#pragma unroll
      for (int mc = 0; mc < 2; ++mc) {
        short8 pf = *(const short8*)&Pw[lo * 64 + ((mc * 32 + hi * 8) ^ ((lo & 7) << 3))];
#pragma unroll
        for (int dvc = 0; dvc < 4; ++dvc) {
          const int vrow = dvc * 16 + lo;
          short8 vf = *(const short8*)&Vb[vrow * 64 + ((mc * 32 + hi * 8) ^ ((vrow & 7) << 3))];
          oacc[dvc] = __builtin_amdgcn_mfma_f32_16x16x32_bf16(pf, vf, oacc[dvc], 0, 0, 0);
        }
      }
    }

    // write out (fp32), C-frag layout: row q = 4*hi+r, col dv = dvc*16+lo
#pragma unroll
    for (int dvc = 0; dvc < 4; ++dvc) {
#pragma unroll
      for (int r = 0; r < 4; ++r) {
        int nn = n0 + w * 16 + hi * 4 + r;
        if (nn < L)
          out[(size_t)(off + nn) * STRIDE + h * DDIM + dvc * 16 + lo] = oacc[dvc][r];
      }
    }
  }
}

// ---- fallback (ws too small / B>16): reg-staged fp32 queue path ----
__launch_bounds__(256)
__global__ void hstu_fb(const float* __restrict__ tq,
                        const float* __restrict__ tk,
                        const float* __restrict__ tv,
                        const int* __restrict__ offsets,
                        const int* __restrict__ pN,
                        const int* __restrict__ ncand,
                        const int* __restrict__ nctx,
                        float* __restrict__ out,
                        uint* __restrict__ ctr,
                        int Tm1, int Bb) {
  const int bhc    = Bb * HH;
  const int nitems = NORD * bhc;

  __shared__ ushort Ks[KT * DDIM];
  __shared__ ushort Vt[DDIM * KT];
  __shared__ ushort Ps[4 * 1024];
  __shared__ int s_item;

  const int tid  = threadIdx.x;
  const int w    = tid >> 6;
  const int lane = tid & 63;
  const int lo   = lane & 15;
  const int hi   = lane >> 4;
  const float invN = 1.0f / (float)pN[0];
  ushort* Pw = &Ps[w * 1024];

  for (;;) {
    __syncthreads();
    if (tid == 0) s_item = (int)atomicAdd(ctr, 1u);
    __syncthreads();
    const int item = s_item;
    if (item >= nitems) return;
    const int ord = item / bhc;
    const int rem = item - ord * bhc;
    const int b = rem / HH, h = rem - b * HH;
    const int qt = (ord == 0) ? 0 : (NORD - ord);
    const int off = offsets[b];
    const int L   = offsets[b + 1] - off;
    const int n0  = qt * QT;
    if (n0 >= L) continue;

    const int c = nctx[b];
    const int M = L - c + 1 - ncand[b];
    const int m_hi  = (n0 < c) ? L : min(n0 + QT, L);
    const int niter = (m_hi + KT - 1) / KT;

    short8 qf[2];
    {
      int qr = min(off + n0 + w * 16 + lo, Tm1);
      const float* qp = tq + (size_t)qr * STRIDE + h * DDIM + hi * 8;
      float4 qa = *(const float4*)(qp);
      float4 qb = *(const float4*)(qp + 4);
      float4 qc = *(const float4*)(qp + 32);
      float4 qd = *(const float4*)(qp + 36);
      u32x4 v0 = {pk2(qa.x, qa.y), pk2(qa.z, qa.w), pk2(qb.x, qb.y), pk2(qb.z, qb.w)};
      u32x4 v1 = {pk2(qc.x, qc.y), pk2(qc.z, qc.w), pk2(qd.x, qd.y), pk2(qd.z, qd.w)};
      qf[0] = __builtin_bit_cast(short8, v0);
      qf[1] = __builtin_bit_cast(short8, v1);
    }

    const int  n   = n0 + w * 16 + lo;
    const int  an  = min(max(n - c + 1, 0), M);
    const int  thr = (an > 0 ? an : M) + c - 1;
    const bool nok = n < L;

    f32x4 oacc[4];
#pragma unroll
    for (int i = 0; i < 4; ++i) oacc[i] = (f32x4){0.f, 0.f, 0.f, 0.f};

    for (int t = 0; t < niter; ++t) {
      const int m0 = t * KT;
      __syncthreads();
#pragma unroll
      for (int jj = 0; jj < 4; ++jj) {
        int row = (tid >> 4) + jj * 16;
        int r2  = min(off + m0 + row, Tm1);
        float4 kv = *(const float4*)(tk + (size_t)r2 * STRIDE + h * DDIM + (tid & 15) * 4);
        uint2 pk;
        pk.x = pk2(kv.x, kv.y);
        pk.y = pk2(kv.z, kv.w);
        *(uint2*)&Ks[row * 64 + (((tid & 15) * 4) ^ ((row & 7) << 3))] = pk;
      }
      {
        uint bb[8];
#pragma unroll
        for (int j = 0; j < 8; ++j) {
          int ra = min(off + m0 + w * 16 + 2 * j,     Tm1);
          int rb = min(off + m0 + w * 16 + 2 * j + 1, Tm1);
          float va = tv[(size_t)ra * STRIDE + h * DDIM + lane];
          float vb = tv[(size_t)rb * STRIDE + h * DDIM + lane];
          bb[j] = pk2(va, vb);
        }
        int s = (lane & 7) << 3;
        *(uint4*)&Vt[lane * 64 + ((w * 16)     ^ s)] = make_uint4(bb[0], bb[1], bb[2], bb[3]);
        *(uint4*)&Vt[lane * 64 + ((w * 16 + 8) ^ s)] = make_uint4(bb[4], bb[5], bb[6], bb[7]);
      }
      __syncthreads();

#pragma unroll
      for (int kc = 0; kc < 4; ++kc) {
        const int krw = kc * 16 + lo;
        const int ksw = (krw & 7) << 3;
        short8 kf0 = *(const short8*)&Ks[krw * 64 + ((hi * 8) ^ ksw)];
        short8 kf1 = *(const short8*)&Ks[krw * 64 + ((32 + hi * 8) ^ ksw)];
        f32x4 s4 = (f32x4){0.f, 0.f, 0.f, 0.f};
        s4 = __builtin_amdgcn_mfma_f32_16x16x32_bf16(kf0, qf[0], s4, 0, 0, 0);
        s4 = __builtin_amdgcn_mfma_f32_16x16x32_bf16(kf1, qf[1], s4, 0, 0, 0);
        const int mb = m0 + kc * 16 + 4 * hi;
        float pp[4];
#pragma unroll
        for (int r = 0; r < 4; ++r) {
          const int mm = mb + r;
          const bool valid = nok & ((mm < thr) | (mm == n));
          float s = valid ? s4[r] : 0.f;
          pp[r] = s * invN * __builtin_amdgcn_rcpf(1.f + __expf(-s));
        }
        const int col = kc * 16 + 4 * hi;
        *(uint2*)&Pw[lo * 64 + (col ^ ((lo & 7) << 3))] =
            make_uint2(pk2(pp[0], pp[1]), pk2(pp[2], pp[3]));
      }

#pragma unroll
      for (int mc = 0; mc < 2; ++mc) {
        short8 pf = *(const short8*)&Pw[lo * 64 + ((mc * 32 + hi * 8) ^ ((lo & 7) << 3))];
#pragma unroll
        for (int dvc = 0; dvc < 4; ++dvc) {
          const int vrow = dvc * 16 + lo;
          short8 vf = *(const short8*)&Vt[vrow * 64 + ((mc * 32 + hi * 8) ^ ((vrow & 7) << 3))];
          oacc[dvc] = __builtin_amdgcn_mfma_f32_16x16x32_bf16(pf, vf, oacc[dvc], 0, 0, 0);
        }
      }
    }

#pragma unroll
    for (int dvc = 0; dvc < 4; ++dvc) {
#pragma unroll
      for (int r = 0; r < 4; ++r) {
        int nn = n0 + w * 16 + hi * 4 + r;
        if (nn < L)
          out[(size_t)(off + nn) * STRIDE + h * DDIM + dvc * 16 + lo] = oacc[dvc][r];
      }
    }
  }
}

extern "C" void kernel_launch(void* const* d_in, const int* in_sizes, int n_in,
                              void* d_out, int out_size, void* d_ws, size_t ws_size,
                              hipStream_t stream) {
  const float* tq      = (const float*)d_in[0];
  const float* tk      = (const float*)d_in[1];
  const float* tv      = (const float*)d_in[2];
  const int*   offsets = (const int*)d_in[3];
  const int*   pN      = (const int*)d_in[4];
  const int*   ncand   = (const int*)d_in[5];
  const int*   nctx    = (const int*)d_in[6];
  float*       out     = (float*)d_out;

  const int B = in_sizes[3] - 1;
  const int T = in_sizes[0] / STRIDE;

  uint*   ctr    = (uint*)d_ws;
  short*  sched  = (short*)((char*)d_ws + 256);
  ushort* kbf    = (ushort*)((char*)d_ws + 256 + NBLK * SLOTS * sizeof(short));
  size_t  kbytes = (size_t)T * STRIDE * sizeof(ushort);
  ushort* vbfT   = (ushort*)((char*)kbf + kbytes);           // kbf tail-overflow
  size_t  vbytes = (size_t)STRIDE * (size_t)B * NMAX * sizeof(ushort);  // lands here: safe
  const size_t need = 256 + NBLK * SLOTS * sizeof(short) + kbytes + vbytes;

  dim3 block(256);

  if (ws_size >= need && B <= 16) {
    dim3 pgrid(NORD, HH, B);
    prep<<<pgrid, block, 0, stream>>>(tk, tv, kbf, vbfT, offsets, sched, B);
    hstu_s<<<NBLK, block, 0, stream>>>(tq, kbf, vbfT, sched, offsets, pN,
                                       ncand, nctx, out, T - 1, B);
  } else {
    zero_ctr<<<1, 1, 0, stream>>>(ctr);
    hstu_fb<<<NBLK, block, 0, stream>>>(tq, tk, tv, offsets, pN, ncand,
                                        nctx, out, ctr, T - 1, B);
  }
}